// Round 8
// baseline (120.820 us; speedup 1.0000x reference)
//
#include <hip/hip_runtime.h>
#include <hip/hip_bf16.h>

#define NB 16
#define NN 256
#define FF 64
#define NC 32
#define EPSF 1e-10f
#define PSTRIDE 164   // per-bi partials: 64 hagg + 96 rc + 3 rx (+1 pad)

typedef __attribute__((ext_vector_type(8))) short s16x8;
typedef __attribute__((ext_vector_type(4))) float f32x4;
typedef __attribute__((ext_vector_type(2))) float f32x2;
typedef __attribute__((ext_vector_type(4))) unsigned u32x4;

__device__ __forceinline__ float rcp_(float v){ return __builtin_amdgcn_rcpf(v); }
__device__ __forceinline__ f32x2 make2(float a, float b){ f32x2 r; r[0]=a; r[1]=b; return r; }
// 4 silus sharing one v_rcp (products of (1+e^-v) stay < 3.4e38 for |v| <~ 20)
__device__ __forceinline__ void silu4_(float v0, float v1, float v2, float v3,
                                       float& o0, float& o1, float& o2, float& o3){
  const float e0 = __expf(-v0), e1 = __expf(-v1), e2 = __expf(-v2), e3 = __expf(-v3);
  const float d0 = 1.f+e0, d1 = 1.f+e1, d2 = 1.f+e2, d3 = 1.f+e3;
  const float d01 = d0*d1, d23 = d2*d3;
  const float r = rcp_(d01*d23);
  const float r01 = r*d23, r23 = r*d01;
  o0 = v0*(r01*d1); o1 = v1*(r01*d0);
  o2 = v2*(r23*d3); o3 = v3*(r23*d2);
}
// packed bf16 convert (RNE), lo16=bf16(a), hi16=bf16(b)
__device__ __forceinline__ unsigned cvtpk(float a, float b){
  unsigned r;
  asm("v_cvt_pk_bf16_f32 %0, %1, %2" : "=v"(r) : "v"(a), "v"(b));
  return r;
}
// DPP-based add of a lane-permuted copy (no DS pipe, no addr setup)
template<int CTRL>
__device__ __forceinline__ float dpp_add(float v){
  int x = __builtin_bit_cast(int, v);
  int y = __builtin_amdgcn_update_dpp(0, x, CTRL, 0xF, 0xF, true);
  return v + __builtin_bit_cast(float, y);
}
// sum over each 16-lane row; all lanes of the row end with the row sum
__device__ __forceinline__ float rowsum16(float v){
  v = dpp_add<0xB1>(v);   // quad_perm xor1
  v = dpp_add<0x4E>(v);   // quad_perm xor2
  v = dpp_add<0x141>(v);  // row_half_mirror
  v = dpp_add<0x140>(v);  // row_mirror
  return v;
}
// ds_swizzle broadcast: src lane = (l & 0xF) | OR  (within each 32-half)
template<int OFF>
__device__ __forceinline__ float swz_(float v){
  int y = __builtin_amdgcn_ds_swizzle(__builtin_bit_cast(int, v), OFF);
  return __builtin_bit_cast(float, y);
}
#define SWZ_LO 0x000F   // src = r15
#define SWZ_HI 0x020F   // src = 16 + r15

// Kernel A: per-node projections + (blocks 0..27) weight pre-packing to d_ws.
__global__ __launch_bounds__(64) void sake_proj(
    const float* __restrict__ h, const float* __restrict__ ew1,
    const float* __restrict__ eb1,
    const float* __restrict__ ew2, const float* __restrict__ cw1,
    const float* __restrict__ xw1, const float* __restrict__ cw2,
    float* __restrict__ hip_, float* __restrict__ hjp_,
    short* __restrict__ wpack)
{
  const int bn = blockIdx.x;
  const int t = threadIdx.x;

  if (bn < 28){
    const int task = bn*64 + t;          // 0..1791
    const int a = task >> 9;             // 0=ew2, 1=cw1, 2=xw1, 3=cw2
    const int s = task & 511;
    const int f = s >> 6, sl = s & 63;
    const int sg = sl >> 4, sr = sl & 15;
    const int mt = f >> 1, kt = f & 1;
    const int ob = mt*16 + sr;
    const int ib = kt*32 + sg*8;
    const float* W = (a==0) ? ew2 : (a==1) ? cw1 : (a==2) ? xw1 : cw2;
    const int ldw = (a==3) ? NC : FF;
    float w[8];
    #pragma unroll
    for (int e=0;e<8;++e) w[e] = W[(ib+e)*ldw + ob];
    u32x4 p;
    p[0]=cvtpk(w[0],w[1]); p[1]=cvtpk(w[2],w[3]); p[2]=cvtpk(w[4],w[5]); p[3]=cvtpk(w[6],w[7]);
    *(u32x4*)&wpack[a*4096 + s*8] = p;
  }

  __shared__ float hs[FF];
  hs[t] = h[bn*FF + t];
  __syncthreads();
  float a1 = eb1[t];
  float a2 = 0.f;
  #pragma unroll 16
  for (int k=0;k<FF;++k){
    const float hv = hs[k];
    a1 += hv * ew1[k*FF + t];
    a2 += hv * ew1[(FF+k)*FF + t];
  }
  hip_[bn*FF + t] = a1;
  hjp_[bn*FF + t] = a2;
}

// Kernel B: one block per (b,i); 8 waves x 32 j; bf16 MFMA, bias-in-C,
// shared-rcp silu quads, packed-f32 epilogues, DPP row-reductions.
__global__ __launch_bounds__(512, 4) void sake_main(
    const float* __restrict__ x,
    const float* __restrict__ ew1, const float* __restrict__ eb2,
    const float* __restrict__ aw, const float* __restrict__ ab,
    const float* __restrict__ cb1, const float* __restrict__ cb2,
    const float* __restrict__ xb1, const float* __restrict__ xw2,
    const float* __restrict__ hip_, const float* __restrict__ hjp_,
    const short* __restrict__ wpack,
    float* __restrict__ part)
{
  const int bi = blockIdx.x;
  const int b = bi >> 8;
  const int tid = threadIdx.x;
  const int wave = tid >> 6;
  const int l = tid & 63;
  const int g = l >> 4;
  const int r15 = l & 15;

  __shared__ __align__(16) short s_w[14336];   // E@0, C@4096, X@8192, w2@12288 (28KB)
  __shared__ __align__(16) short s_sT[8][1024];// per-wave 2KB act^T scratch, XOR-swizzled
  __shared__ __align__(16) float s_hip[FF], s_e1r[FF], s_eb2[FF], s_cb1[FF], s_xb1[FF], s_xw2v[FF], s_awv[FF];
  __shared__ __align__(16) float s_cb2[NC];
  __shared__ float s_rh[8*FF];
  __shared__ float s_rc[8*NC*3];
  __shared__ float s_rx[8*3];

  // ---- prologue: linear copy of pre-packed weights (28KB) ----
  {
    const u32x4* wp = (const u32x4*)wpack;
    u32x4* wd = (u32x4*)s_w;
    wd[tid]       = wp[tid];
    wd[tid+512]   = wp[tid+512];
    wd[tid+1024]  = wp[tid+1024];
    if (tid < 256) wd[tid+1536] = wp[tid+1536];
  }
  if (tid < FF){
    s_hip[tid]  = hip_[(size_t)bi*FF + tid];
    s_e1r[tid]  = ew1[128*FF + tid];
    s_eb2[tid]  = eb2[tid];
    s_cb1[tid]  = cb1[tid];
    s_xb1[tid]  = xb1[tid];
    s_xw2v[tid] = xw2[tid];
    s_awv[tid]  = aw[tid];
  } else if (tid < FF + NC){
    s_cb2[tid-FF] = cb2[tid-FF];
  }
  __syncthreads();

  const float abv = ab[0];
  const float xi0 = x[(size_t)bi*3+0], xi1 = x[(size_t)bi*3+1], xi2 = x[(size_t)bi*3+2];

  // ---- geometry in registers: lane l holds jl = l&31 ----
  float dx, dy, dz, nr, ux, uy, uz;
  {
    const int jl = l & 31;
    const int j  = wave*32 + jl;
    const float xj0 = x[((size_t)(b*NN+j))*3+0];
    const float xj1 = x[((size_t)(b*NN+j))*3+1];
    const float xj2 = x[((size_t)(b*NN+j))*3+2];
    dx = xi0-xj0; dy = xi1-xj1; dz = xi2-xj2;
    nr = __builtin_amdgcn_sqrtf(dx*dx+dy*dy+dz*dz+EPSF);
    const float inr = rcp_(nr + EPSF);
    ux = dx*inr; uy = dy*inr; uz = dz*inr;
  }

  // ---- hoisted hp/e1 slices (reused across jt) ----
  float4 hp0v[2], hp1v[2], e10v[2], e11v[2];
  #pragma unroll
  for (int kt=0;kt<2;++kt){
    const int fb = kt*32 + g*8;
    hp0v[kt] = *(const float4*)&s_hip[fb];
    hp1v[kt] = *(const float4*)&s_hip[fb+4];
    e10v[kt] = *(const float4*)&s_e1r[fb];
    e11v[kt] = *(const float4*)&s_e1r[fb+4];
  }

  // ---- a1 B-frags ----
  s16x8 a1f[2][2];
  #pragma unroll
  for (int jt=0;jt<2;++jt){
    const float nrj = jt ? swz_<SWZ_HI>(nr) : swz_<SWZ_LO>(nr);
    const float* hrow = &hjp_[((size_t)(b*NN + wave*32 + jt*16 + r15))*FF];
    #pragma unroll
    for (int kt=0;kt<2;++kt){
      const int fb = kt*32 + g*8;
      const float4 hj0 = *(const float4*)&hrow[fb];
      const float4 hj1 = *(const float4*)&hrow[fb+4];
      float lv[8];
      lv[0] = hp0v[kt].x + hj0.x + nrj*e10v[kt].x;
      lv[1] = hp0v[kt].y + hj0.y + nrj*e10v[kt].y;
      lv[2] = hp0v[kt].z + hj0.z + nrj*e10v[kt].z;
      lv[3] = hp0v[kt].w + hj0.w + nrj*e10v[kt].w;
      lv[4] = hp1v[kt].x + hj1.x + nrj*e11v[kt].x;
      lv[5] = hp1v[kt].y + hj1.y + nrj*e11v[kt].y;
      lv[6] = hp1v[kt].z + hj1.z + nrj*e11v[kt].z;
      lv[7] = hp1v[kt].w + hj1.w + nrj*e11v[kt].w;
      float s[8];
      silu4_(lv[0],lv[1],lv[2],lv[3], s[0],s[1],s[2],s[3]);
      silu4_(lv[4],lv[5],lv[6],lv[7], s[4],s[5],s[6],s[7]);
      u32x4 p; p[0]=cvtpk(s[0],s[1]); p[1]=cvtpk(s[2],s[3]); p[2]=cvtpk(s[4],s[5]); p[3]=cvtpk(s[6],s[7]);
      a1f[jt][kt] = __builtin_bit_cast(s16x8, p);
    }
  }

  // ---- E-GEMM with bias-in-C ----
  f32x4 accE[4][2];
  #pragma unroll
  for (int mt=0;mt<4;++mt){
    const f32x4 bE = *(const f32x4*)&s_eb2[mt*16 + g*4];
    accE[mt][0] = bE; accE[mt][1] = bE;
  }
  #pragma unroll
  for (int kt=0;kt<2;++kt){
    #pragma unroll
    for (int mt=0;mt<4;++mt){
      const s16x8 wf = *(const s16x8*)&s_w[((mt*2+kt)*64 + l)*8];
      accE[mt][0] = __builtin_amdgcn_mfma_f32_16x16x32_bf16(wf, a1f[0][kt], accE[mt][0], 0,0,0);
      accE[mt][1] = __builtin_amdgcn_mfma_f32_16x16x32_bf16(wf, a1f[1][kt], accE[mt][1], 0,0,0);
    }
  }

  // ---- silu (quads), att gate (packed) ----
  float hg[4][2][4];
  f32x2 attp = {0.f, 0.f};
  #pragma unroll
  for (int mt=0;mt<4;++mt){
    const f32x4 awv4 = *(const f32x4*)&s_awv[mt*16 + g*4];
    #pragma unroll
    for (int r=0;r<4;r+=2){
      float s0,s1,s2,s3;
      silu4_(accE[mt][0][r], accE[mt][1][r], accE[mt][0][r+1], accE[mt][1][r+1], s0,s1,s2,s3);
      hg[mt][0][r]=s0; hg[mt][1][r]=s1; hg[mt][0][r+1]=s2; hg[mt][1][r+1]=s3;
      attp += make2(s0,s1)*awv4[r] + make2(s2,s3)*awv4[r+1];
    }
  }
  float att0p = attp[0], att1p = attp[1];
  att0p += __shfl_xor(att0p,16,64); att0p += __shfl_xor(att0p,32,64);
  att1p += __shfl_xor(att1p,16,64); att1p += __shfl_xor(att1p,32,64);
  // paired sigmoid (shared rcp)
  float att0, att1;
  {
    const float ea = __expf(-(att0p + abv)), eb = __expf(-(att1p + abv));
    const float da = 1.f+ea, db = 1.f+eb;
    const float rr = rcp_(da*db);
    att0 = rr*db; att1 = rr*da;
  }
  const f32x2 attv = make2(att0, att1);

  #pragma unroll
  for (int mt=0;mt<4;++mt){
    #pragma unroll
    for (int r=0;r<4;++r){
      const f32x2 hv = make2(hg[mt][0][r], hg[mt][1][r]) * attv;
      hg[mt][0][r] = hv[0]; hg[mt][1][r] = hv[1];
      const float hpv = rowsum16(hv[0] + hv[1]);
      if (r15 == 0) s_rh[wave*FF + mt*16 + g*4 + r] = hpv;
    }
  }

  // ---- he^T -> 2KB scratch, sequential 16-j tiles; read B-frags ----
  char* myT = (char*)&s_sT[wave][0];
  const int swzb = (r15 & 7) << 4;
  s16x8 hef[2][2];
  #pragma unroll
  for (int jt=0;jt<2;++jt){
    #pragma unroll
    for (int mt=0;mt<4;++mt){
      const unsigned p0 = cvtpk(hg[mt][jt][0], hg[mt][jt][1]);
      const unsigned p1 = cvtpk(hg[mt][jt][2], hg[mt][jt][3]);
      const int bo = (r15*128 + (mt*16 + g*4)*2) ^ swzb;
      *(uint2*)(myT + bo) = make_uint2(p0, p1);
    }
    #pragma unroll
    for (int kt=0;kt<2;++kt){
      const int bo = (r15*128 + (kt*32 + g*8)*2) ^ swzb;
      hef[jt][kt] = *(const s16x8*)(myT + bo);
    }
  }

  // ---- cw1-GEMM and xw1-GEMM with bias-in-C ----
  f32x4 accC[4][2], accX[4][2];
  #pragma unroll
  for (int mt=0;mt<4;++mt){
    const f32x4 bC = *(const f32x4*)&s_cb1[mt*16 + g*4];
    const f32x4 bX = *(const f32x4*)&s_xb1[mt*16 + g*4];
    accC[mt][0]=bC; accC[mt][1]=bC;
    accX[mt][0]=bX; accX[mt][1]=bX;
  }
  #pragma unroll
  for (int kt=0;kt<2;++kt){
    #pragma unroll
    for (int mt=0;mt<4;++mt){
      const s16x8 wfc = *(const s16x8*)&s_w[4096 + ((mt*2+kt)*64 + l)*8];
      accC[mt][0] = __builtin_amdgcn_mfma_f32_16x16x32_bf16(wfc, hef[0][kt], accC[mt][0], 0,0,0);
      accC[mt][1] = __builtin_amdgcn_mfma_f32_16x16x32_bf16(wfc, hef[1][kt], accC[mt][1], 0,0,0);
      const s16x8 wfx = *(const s16x8*)&s_w[8192 + ((mt*2+kt)*64 + l)*8];
      accX[mt][0] = __builtin_amdgcn_mfma_f32_16x16x32_bf16(wfx, hef[0][kt], accX[mt][0], 0,0,0);
      accX[mt][1] = __builtin_amdgcn_mfma_f32_16x16x32_bf16(wfx, hef[1][kt], accX[mt][1], 0,0,0);
    }
  }

  // ---- trans + x-update (silu quads, packed dot) ----
  {
    f32x2 tpv = {0.f, 0.f};
    #pragma unroll
    for (int mt=0;mt<4;++mt){
      const f32x4 xv4 = *(const f32x4*)&s_xw2v[mt*16 + g*4];
      #pragma unroll
      for (int r=0;r<4;r+=2){
        float s0,s1,s2,s3;
        silu4_(accX[mt][0][r], accX[mt][1][r], accX[mt][0][r+1], accX[mt][1][r+1], s0,s1,s2,s3);
        tpv += make2(s0,s1)*xv4[r] + make2(s2,s3)*xv4[r+1];
      }
    }
    float tp0 = tpv[0], tp1 = tpv[1];
    tp0 += __shfl_xor(tp0,16,64); tp0 += __shfl_xor(tp0,32,64);
    tp1 += __shfl_xor(tp1,16,64); tp1 += __shfl_xor(tp1,32,64);
    const float dx0 = swz_<SWZ_LO>(dx), dx1 = swz_<SWZ_HI>(dx);
    const float dy0 = swz_<SWZ_LO>(dy), dy1 = swz_<SWZ_HI>(dy);
    const float dz0 = swz_<SWZ_LO>(dz), dz1 = swz_<SWZ_HI>(dz);
    const float xa0 = rowsum16(dx0*tp0 + dx1*tp1);
    const float xa1 = rowsum16(dy0*tp0 + dy1*tp1);
    const float xa2 = rowsum16(dz0*tp0 + dz1*tp1);
    if (l == 0){ s_rx[wave*3+0]=xa0; s_rx[wave*3+1]=xa1; s_rx[wave*3+2]=xa2; }
  }

  // ---- c1 (silu quads) -> scratch, read c1f, cw2-GEMM ----
  s16x8 c1f[2][2];
  #pragma unroll
  for (int mt=0;mt<4;++mt){
    float c0[4], c1v[4];   // [r] for jt0, jt1
    #pragma unroll
    for (int r=0;r<4;r+=2){
      silu4_(accC[mt][0][r], accC[mt][1][r], accC[mt][0][r+1], accC[mt][1][r+1],
             c0[r], c1v[r], c0[r+1], c1v[r+1]);
    }
    const int nb4 = mt*16 + g*4;
    const int bo0 = (r15*128 + nb4*2) ^ swzb;
    *(uint2*)(myT + bo0) = make_uint2(cvtpk(c0[0],c0[1]), cvtpk(c0[2],c0[3]));
  // stash jt1 values in hg (dead now) to write after
    hg[mt][1][0]=c1v[0]; hg[mt][1][1]=c1v[1]; hg[mt][1][2]=c1v[2]; hg[mt][1][3]=c1v[3];
  }
  #pragma unroll
  for (int kt=0;kt<2;++kt){
    const int bo = (r15*128 + (kt*32 + g*8)*2) ^ swzb;
    c1f[0][kt] = *(const s16x8*)(myT + bo);
  }
  #pragma unroll
  for (int mt=0;mt<4;++mt){
    const int nb4 = mt*16 + g*4;
    const int bo1 = (r15*128 + nb4*2) ^ swzb;
    *(uint2*)(myT + bo1) = make_uint2(cvtpk(hg[mt][1][0],hg[mt][1][1]), cvtpk(hg[mt][1][2],hg[mt][1][3]));
  }
  #pragma unroll
  for (int kt=0;kt<2;++kt){
    const int bo = (r15*128 + (kt*32 + g*8)*2) ^ swzb;
    c1f[1][kt] = *(const s16x8*)(myT + bo);
  }
  f32x4 accW[2][2];
  #pragma unroll
  for (int mt=0;mt<2;++mt){
    const f32x4 bW = *(const f32x4*)&s_cb2[mt*16 + g*4];
    accW[mt][0]=bW; accW[mt][1]=bW;
  }
  #pragma unroll
  for (int kt=0;kt<2;++kt){
    #pragma unroll
    for (int mt=0;mt<2;++mt){
      const s16x8 wf = *(const s16x8*)&s_w[12288 + ((mt*2+kt)*64 + l)*8];
      accW[mt][0] = __builtin_amdgcn_mfma_f32_16x16x32_bf16(wf, c1f[0][kt], accW[mt][0], 0,0,0);
      accW[mt][1] = __builtin_amdgcn_mfma_f32_16x16x32_bf16(wf, c1f[1][kt], accW[mt][1], 0,0,0);
    }
  }

  // ---- comb accumulation (DPP row-reduce) ----
  {
    const float u0x = swz_<SWZ_LO>(ux), u1x = swz_<SWZ_HI>(ux);
    const float u0y = swz_<SWZ_LO>(uy), u1y = swz_<SWZ_HI>(uy);
    const float u0z = swz_<SWZ_LO>(uz), u1z = swz_<SWZ_HI>(uz);
    #pragma unroll
    for (int mt=0;mt<2;++mt){
      #pragma unroll
      for (int r=0;r<4;++r){
        const int c = mt*16 + g*4 + r;
        const float cf0 = accW[mt][0][r];
        const float cf1 = accW[mt][1][r];
        const float px = rowsum16(u0x*cf0 + u1x*cf1);
        const float py = rowsum16(u0y*cf0 + u1y*cf1);
        const float pz = rowsum16(u0z*cf0 + u1z*cf1);
        if (r15 == 0){
          s_rc[wave*96 + c*3+0]=px; s_rc[wave*96 + c*3+1]=py; s_rc[wave*96 + c*3+2]=pz;
        }
      }
    }
  }

  __syncthreads();

  // ---- cross-wave reduce -> partials to global ws ----
  float* P = part + (size_t)bi*PSTRIDE;
  if (tid < 64){
    float s = 0.f;
    #pragma unroll
    for (int w=0;w<8;++w) s += s_rh[w*FF + tid];
    P[tid] = s;
  } else if (tid < 160){
    const int t = tid - 64;
    float s = 0.f;
    #pragma unroll
    for (int w=0;w<8;++w) s += s_rc[w*96 + t];
    P[64 + t] = s;
  } else if (tid < 163){
    const int t = tid - 160;
    float s = 0.f;
    #pragma unroll
    for (int w=0;w<8;++w) s += s_rx[w*3 + t];
    P[160 + t] = s;
  }
}

// Kernel C: node-level MLPs. One wave per (b,i).
__global__ __launch_bounds__(64) void sake_node(
    const float* __restrict__ h, const float* __restrict__ x,
    const float* __restrict__ pw1, const float* __restrict__ pb1,
    const float* __restrict__ pw2, const float* __restrict__ pb2,
    const float* __restrict__ nw1, const float* __restrict__ nb1,
    const float* __restrict__ nw2, const float* __restrict__ nb2,
    const float* __restrict__ part, float* __restrict__ out_h, float* __restrict__ out_x)
{
  const int bi = blockIdx.x;
  const int l = threadIdx.x;
  __shared__ float s_cn[NC];
  __shared__ float s_t1[FF];
  __shared__ float s_ni[3*FF];
  const float* P = part + (size_t)bi*PSTRIDE;

  const float hval = h[(size_t)bi*FF + l];
  s_ni[l] = hval;
  s_ni[FF + l] = P[l];                 // hagg
  if (l < NC){
    const float c0 = P[64 + l*3+0];
    const float c1 = P[64 + l*3+1];
    const float c2 = P[64 + l*3+2];
    s_cn[l] = c0*c0 + c1*c1 + c2*c2;
  }
  __syncthreads();
  {
    float a0=0.f,a1=0.f,a2=0.f,a3=0.f;
    #pragma unroll 4
    for (int c=0;c<NC;c+=4){
      a0 += s_cn[c+0]*pw1[(c+0)*FF + l];
      a1 += s_cn[c+1]*pw1[(c+1)*FF + l];
      a2 += s_cn[c+2]*pw1[(c+2)*FF + l];
      a3 += s_cn[c+3]*pw1[(c+3)*FF + l];
    }
    const float v = pb1[l] + ((a0+a1)+(a2+a3));
    s_t1[l] = v*rcp_(1.f+__expf(-v));
  }
  __syncthreads();
  {
    float a0=0.f,a1=0.f,a2=0.f,a3=0.f;
    #pragma unroll 4
    for (int k=0;k<FF;k+=4){
      a0 += s_t1[k+0]*pw2[(k+0)*FF + l];
      a1 += s_t1[k+1]*pw2[(k+1)*FF + l];
      a2 += s_t1[k+2]*pw2[(k+2)*FF + l];
      a3 += s_t1[k+3]*pw2[(k+3)*FF + l];
    }
    s_ni[2*FF + l] = pb2[l] + ((a0+a1)+(a2+a3));
  }
  __syncthreads();
  float n1;
  {
    float a0=0.f,a1=0.f,a2=0.f,a3=0.f;
    #pragma unroll 4
    for (int k=0;k<3*FF;k+=4){
      a0 += s_ni[k+0]*nw1[(k+0)*FF + l];
      a1 += s_ni[k+1]*nw1[(k+1)*FF + l];
      a2 += s_ni[k+2]*nw1[(k+2)*FF + l];
      a3 += s_ni[k+3]*nw1[(k+3)*FF + l];
    }
    const float v = nb1[l] + ((a0+a1)+(a2+a3));
    n1 = v*rcp_(1.f+__expf(-v));
  }
  __syncthreads();
  s_t1[l] = n1;
  __syncthreads();
  {
    float a0=0.f,a1=0.f,a2=0.f,a3=0.f;
    #pragma unroll 4
    for (int k=0;k<FF;k+=4){
      a0 += s_t1[k+0]*nw2[(k+0)*FF + l];
      a1 += s_t1[k+1]*nw2[(k+1)*FF + l];
      a2 += s_t1[k+2]*nw2[(k+2)*FF + l];
      a3 += s_t1[k+3]*nw2[(k+3)*FF + l];
    }
    out_h[(size_t)bi*FF + l] = hval + nb2[l] + ((a0+a1)+(a2+a3));
    if (l < 3){
      out_x[(size_t)bi*3 + l] = x[(size_t)bi*3 + l] + P[160+l]*(1.0f/256.0f);
    }
  }
}

extern "C" void kernel_launch(void* const* d_in, const int* in_sizes, int n_in,
                              void* d_out, int out_size, void* d_ws, size_t ws_size,
                              hipStream_t stream) {
  const float* h   = (const float*)d_in[0];
  const float* x   = (const float*)d_in[1];
  const float* ew1 = (const float*)d_in[2];
  const float* eb1 = (const float*)d_in[3];
  const float* ew2 = (const float*)d_in[4];
  const float* eb2 = (const float*)d_in[5];
  const float* aw  = (const float*)d_in[6];
  const float* ab  = (const float*)d_in[7];
  const float* cw1 = (const float*)d_in[8];
  const float* cb1 = (const float*)d_in[9];
  const float* cw2 = (const float*)d_in[10];
  const float* cb2 = (const float*)d_in[11];
  const float* pw1 = (const float*)d_in[12];
  const float* pb1 = (const float*)d_in[13];
  const float* pw2 = (const float*)d_in[14];
  const float* pb2 = (const float*)d_in[15];
  const float* nw1 = (const float*)d_in[16];
  const float* nb1 = (const float*)d_in[17];
  const float* nw2 = (const float*)d_in[18];
  const float* nb2 = (const float*)d_in[19];
  const float* xw1 = (const float*)d_in[20];
  const float* xb1 = (const float*)d_in[21];
  const float* xw2 = (const float*)d_in[22];

  float* hip_ = (float*)d_ws;
  float* hjp_ = hip_ + (size_t)NB*NN*FF;
  float* part = hjp_ + (size_t)NB*NN*FF;
  short* wpack = (short*)(part + (size_t)NB*NN*PSTRIDE);
  float* out_h = (float*)d_out;
  float* out_x = out_h + (size_t)NB*NN*FF;

  sake_proj<<<NB*NN, 64, 0, stream>>>(h, ew1, eb1, ew2, cw1, xw1, cw2, hip_, hjp_, wpack);
  sake_main<<<NB*NN, 512, 0, stream>>>(x, ew1, eb2, aw, ab, cb1, cb2, xb1, xw2,
                                       hip_, hjp_, wpack, part);
  sake_node<<<NB*NN, 64, 0, stream>>>(h, x, pw1, pb1, pw2, pb2, nw1, nb1, nw2, nb2,
                                      part, out_h, out_x);
}

// Round 10
// 116.103 us; speedup vs baseline: 1.0406x; 1.0406x over previous
//
#include <hip/hip_runtime.h>
#include <hip/hip_bf16.h>

#define NB 16
#define NN 256
#define FF 64
#define NC 32
#define EPSF 1e-10f
#define PSTRIDE 164   // per-bi partials: 64 hagg + 96 rc + 3 rx (+1 pad)

typedef __attribute__((ext_vector_type(8))) short s16x8;
typedef __attribute__((ext_vector_type(4))) float f32x4;
typedef __attribute__((ext_vector_type(4))) unsigned u32x4;

__device__ __forceinline__ float rcp_(float v){ return __builtin_amdgcn_rcpf(v); }
__device__ __forceinline__ float sigmoid_(float v){ return rcp_(1.0f+__expf(-v)); }
__device__ __forceinline__ float silu_(float v){ return v*rcp_(1.0f+__expf(-v)); }
// packed bf16 convert (RNE), lo16=bf16(a), hi16=bf16(b)
__device__ __forceinline__ unsigned cvtpk(float a, float b){
  unsigned r;
  asm("v_cvt_pk_bf16_f32 %0, %1, %2" : "=v"(r) : "v"(a), "v"(b));
  return r;
}
// DPP-based add of a lane-permuted copy (no DS pipe, no addr setup)
template<int CTRL>
__device__ __forceinline__ float dpp_add(float v){
  int x = __builtin_bit_cast(int, v);
  int y = __builtin_amdgcn_update_dpp(0, x, CTRL, 0xF, 0xF, true);
  return v + __builtin_bit_cast(float, y);
}
// sum over each 16-lane row; all lanes of the row end with the row sum
__device__ __forceinline__ float rowsum16(float v){
  v = dpp_add<0xB1>(v);   // quad_perm xor1
  v = dpp_add<0x4E>(v);   // quad_perm xor2
  v = dpp_add<0x141>(v);  // row_half_mirror
  v = dpp_add<0x140>(v);  // row_mirror
  return v;
}
// ds_swizzle broadcast: src lane = (l & 0xF) | OR  (within each 32-half)
template<int OFF>
__device__ __forceinline__ float swz_(float v){
  int y = __builtin_amdgcn_ds_swizzle(__builtin_bit_cast(int, v), OFF);
  return __builtin_bit_cast(float, y);
}
#define SWZ_LO 0x000F   // src = r15
#define SWZ_HI 0x020F   // src = 16 + r15

// Kernel A: per-node projections + (blocks 0..27) weight pre-packing to d_ws.
__global__ __launch_bounds__(64) void sake_proj(
    const float* __restrict__ h, const float* __restrict__ ew1,
    const float* __restrict__ eb1,
    const float* __restrict__ ew2, const float* __restrict__ cw1,
    const float* __restrict__ xw1, const float* __restrict__ cw2,
    float* __restrict__ hip_, float* __restrict__ hjp_,
    short* __restrict__ wpack)
{
  const int bn = blockIdx.x;
  const int t = threadIdx.x;

  if (bn < 28){
    const int task = bn*64 + t;          // 0..1791
    const int a = task >> 9;             // 0=ew2, 1=cw1, 2=xw1, 3=cw2
    const int s = task & 511;
    const int f = s >> 6, sl = s & 63;
    const int sg = sl >> 4, sr = sl & 15;
    const int mt = f >> 1, kt = f & 1;
    const int ob = mt*16 + sr;
    const int ib = kt*32 + sg*8;
    const float* W = (a==0) ? ew2 : (a==1) ? cw1 : (a==2) ? xw1 : cw2;
    const int ldw = (a==3) ? NC : FF;
    float w[8];
    #pragma unroll
    for (int e=0;e<8;++e) w[e] = W[(ib+e)*ldw + ob];
    u32x4 p;
    p[0]=cvtpk(w[0],w[1]); p[1]=cvtpk(w[2],w[3]); p[2]=cvtpk(w[4],w[5]); p[3]=cvtpk(w[6],w[7]);
    *(u32x4*)&wpack[a*4096 + s*8] = p;
  }

  __shared__ float hs[FF];
  hs[t] = h[bn*FF + t];
  __syncthreads();
  float a1 = eb1[t];
  float a2 = 0.f;
  #pragma unroll 16
  for (int k=0;k<FF;++k){
    const float hv = hs[k];
    a1 += hv * ew1[k*FF + t];
    a2 += hv * ew1[(FF+k)*FF + t];
  }
  hip_[bn*FF + t] = a1;
  hjp_[bn*FF + t] = a2;
}

// Kernel B: one block per (b,i); 8 waves x 32 j; bf16 MFMA, bias-in-C,
// DPP row-reductions, pre-packed weights (E/C/X in LDS, w2 in registers).
__global__ __launch_bounds__(512, 4) void sake_main(
    const float* __restrict__ x,
    const float* __restrict__ ew1, const float* __restrict__ eb2,
    const float* __restrict__ aw, const float* __restrict__ ab,
    const float* __restrict__ cb1, const float* __restrict__ cb2,
    const float* __restrict__ xb1, const float* __restrict__ xw2,
    const float* __restrict__ hip_, const float* __restrict__ hjp_,
    const short* __restrict__ wpack,
    float* __restrict__ part)
{
  const int bi = blockIdx.x;
  const int b = bi >> 8;
  const int tid = threadIdx.x;
  const int wave = tid >> 6;
  const int l = tid & 63;
  const int g = l >> 4;
  const int r15 = l & 15;

  __shared__ __align__(16) short s_w[12288];   // E@0, C@4096, X@8192 (24KB)
  __shared__ __align__(16) short s_sT[8][1024];// per-wave 2KB act^T scratch, XOR-swizzled
  __shared__ __align__(16) float s_hip[FF], s_e1r[FF], s_eb2[FF], s_cb1[FF], s_xb1[FF], s_xw2v[FF], s_awv[FF];
  __shared__ __align__(16) float s_cb2[NC];
  __shared__ float s_rh[8*FF];
  __shared__ float s_rc[8*NC*3];
  __shared__ float s_rx[8*3];

  // ---- w2 A-frags straight to registers (latency hides under LDS copy) ----
  s16x8 w2f[4];
  #pragma unroll
  for (int f=0; f<4; ++f)
    w2f[f] = *(const s16x8*)&wpack[12288 + (f*64 + l)*8];

  // ---- prologue: linear copy of pre-packed E/C/X weights (24KB) ----
  {
    const u32x4* wp = (const u32x4*)wpack;
    u32x4* wd = (u32x4*)s_w;
    wd[tid]       = wp[tid];
    wd[tid+512]   = wp[tid+512];
    wd[tid+1024]  = wp[tid+1024];
  }
  if (tid < FF){
    s_hip[tid]  = hip_[(size_t)bi*FF + tid];
    s_e1r[tid]  = ew1[128*FF + tid];
    s_eb2[tid]  = eb2[tid];
    s_cb1[tid]  = cb1[tid];
    s_xb1[tid]  = xb1[tid];
    s_xw2v[tid] = xw2[tid];
    s_awv[tid]  = aw[tid];
  } else if (tid < FF + NC){
    s_cb2[tid-FF] = cb2[tid-FF];
  }
  __syncthreads();

  const float abv = ab[0];
  const float xi0 = x[(size_t)bi*3+0], xi1 = x[(size_t)bi*3+1], xi2 = x[(size_t)bi*3+2];

  // ---- geometry in registers: lane l holds jl = l&31 ----
  float dx, dy, dz, nr, ux, uy, uz;
  {
    const int jl = l & 31;
    const int j  = wave*32 + jl;
    const float xj0 = x[((size_t)(b*NN+j))*3+0];
    const float xj1 = x[((size_t)(b*NN+j))*3+1];
    const float xj2 = x[((size_t)(b*NN+j))*3+2];
    dx = xi0-xj0; dy = xi1-xj1; dz = xi2-xj2;
    nr = __builtin_amdgcn_sqrtf(dx*dx+dy*dy+dz*dz+EPSF);
    const float inr = rcp_(nr + EPSF);
    ux = dx*inr; uy = dy*inr; uz = dz*inr;
  }

  // ---- hoisted hp/e1 slices (reused across jt) ----
  float4 hp0v[2], hp1v[2], e10v[2], e11v[2];
  #pragma unroll
  for (int kt=0;kt<2;++kt){
    const int fb = kt*32 + g*8;
    hp0v[kt] = *(const float4*)&s_hip[fb];
    hp1v[kt] = *(const float4*)&s_hip[fb+4];
    e10v[kt] = *(const float4*)&s_e1r[fb];
    e11v[kt] = *(const float4*)&s_e1r[fb+4];
  }

  // ---- a1 B-frags: slot(l,e) = a1[j=jt*16+r15][feat=kt*32+g*8+e] ----
  s16x8 a1f[2][2];
  #pragma unroll
  for (int jt=0;jt<2;++jt){
    const float nrj = jt ? swz_<SWZ_HI>(nr) : swz_<SWZ_LO>(nr);
    const float* hrow = &hjp_[((size_t)(b*NN + wave*32 + jt*16 + r15))*FF];
    #pragma unroll
    for (int kt=0;kt<2;++kt){
      const int fb = kt*32 + g*8;
      const float4 hj0 = *(const float4*)&hrow[fb];
      const float4 hj1 = *(const float4*)&hrow[fb+4];
      const float v0 = silu_(hp0v[kt].x + hj0.x + nrj*e10v[kt].x);
      const float v1 = silu_(hp0v[kt].y + hj0.y + nrj*e10v[kt].y);
      const float v2 = silu_(hp0v[kt].z + hj0.z + nrj*e10v[kt].z);
      const float v3 = silu_(hp0v[kt].w + hj0.w + nrj*e10v[kt].w);
      const float v4 = silu_(hp1v[kt].x + hj1.x + nrj*e11v[kt].x);
      const float v5 = silu_(hp1v[kt].y + hj1.y + nrj*e11v[kt].y);
      const float v6 = silu_(hp1v[kt].z + hj1.z + nrj*e11v[kt].z);
      const float v7 = silu_(hp1v[kt].w + hj1.w + nrj*e11v[kt].w);
      u32x4 p; p[0]=cvtpk(v0,v1); p[1]=cvtpk(v2,v3); p[2]=cvtpk(v4,v5); p[3]=cvtpk(v6,v7);
      a1f[jt][kt] = __builtin_bit_cast(s16x8, p);
    }
  }

  // ---- E-GEMM with bias-in-C ----
  f32x4 accE[4][2];
  #pragma unroll
  for (int mt=0;mt<4;++mt){
    const f32x4 bE = *(const f32x4*)&s_eb2[mt*16 + g*4];
    accE[mt][0] = bE; accE[mt][1] = bE;
  }
  #pragma unroll
  for (int kt=0;kt<2;++kt){
    #pragma unroll
    for (int mt=0;mt<4;++mt){
      const s16x8 wf = *(const s16x8*)&s_w[((mt*2+kt)*64 + l)*8];
      accE[mt][0] = __builtin_amdgcn_mfma_f32_16x16x32_bf16(wf, a1f[0][kt], accE[mt][0], 0,0,0);
      accE[mt][1] = __builtin_amdgcn_mfma_f32_16x16x32_bf16(wf, a1f[1][kt], accE[mt][1], 0,0,0);
    }
  }

  // ---- silu, att gate ----
  float hg[4][2][4];
  float att0p = 0.f, att1p = 0.f;
  #pragma unroll
  for (int mt=0;mt<4;++mt){
    const f32x4 awv4 = *(const f32x4*)&s_awv[mt*16 + g*4];
    #pragma unroll
    for (int r=0;r<4;++r){
      const float v0 = silu_(accE[mt][0][r]);
      const float v1 = silu_(accE[mt][1][r]);
      hg[mt][0][r] = v0; hg[mt][1][r] = v1;
      att0p += v0*awv4[r]; att1p += v1*awv4[r];
    }
  }
  att0p += __shfl_xor(att0p,16,64); att0p += __shfl_xor(att0p,32,64);
  att1p += __shfl_xor(att1p,16,64); att1p += __shfl_xor(att1p,32,64);
  const float att0 = sigmoid_(att0p + abv);
  const float att1 = sigmoid_(att1p + abv);

  #pragma unroll
  for (int mt=0;mt<4;++mt){
    #pragma unroll
    for (int r=0;r<4;++r){
      const float h0 = hg[mt][0][r]*att0;
      const float h1 = hg[mt][1][r]*att1;
      hg[mt][0][r] = h0; hg[mt][1][r] = h1;
      const float hpv = rowsum16(h0 + h1);
      if (r15 == 0) s_rh[wave*FF + mt*16 + g*4 + r] = hpv;
    }
  }

  // ---- he^T -> 2KB scratch (base-folded), sequential 16-j tiles ----
  char* myR = (char*)&s_sT[wave][0] + r15*128;
  const int swzb = (r15 & 7) << 4;
  s16x8 hef[2][2];
  #pragma unroll
  for (int jt=0;jt<2;++jt){
    #pragma unroll
    for (int mt=0;mt<4;++mt){
      const unsigned p0 = cvtpk(hg[mt][jt][0], hg[mt][jt][1]);
      const unsigned p1 = cvtpk(hg[mt][jt][2], hg[mt][jt][3]);
      *(uint2*)(myR + (((mt*16 + g*4)*2) ^ swzb)) = make_uint2(p0, p1);
    }
    #pragma unroll
    for (int kt=0;kt<2;++kt){
      hef[jt][kt] = *(const s16x8*)(myR + (((kt*32 + g*8)*2) ^ swzb));
    }
  }

  // ---- cw1-GEMM and xw1-GEMM with bias-in-C ----
  f32x4 accC[4][2], accX[4][2];
  #pragma unroll
  for (int mt=0;mt<4;++mt){
    const f32x4 bC = *(const f32x4*)&s_cb1[mt*16 + g*4];
    const f32x4 bX = *(const f32x4*)&s_xb1[mt*16 + g*4];
    accC[mt][0]=bC; accC[mt][1]=bC;
    accX[mt][0]=bX; accX[mt][1]=bX;
  }
  #pragma unroll
  for (int kt=0;kt<2;++kt){
    #pragma unroll
    for (int mt=0;mt<4;++mt){
      const s16x8 wfc = *(const s16x8*)&s_w[4096 + ((mt*2+kt)*64 + l)*8];
      accC[mt][0] = __builtin_amdgcn_mfma_f32_16x16x32_bf16(wfc, hef[0][kt], accC[mt][0], 0,0,0);
      accC[mt][1] = __builtin_amdgcn_mfma_f32_16x16x32_bf16(wfc, hef[1][kt], accC[mt][1], 0,0,0);
      const s16x8 wfx = *(const s16x8*)&s_w[8192 + ((mt*2+kt)*64 + l)*8];
      accX[mt][0] = __builtin_amdgcn_mfma_f32_16x16x32_bf16(wfx, hef[0][kt], accX[mt][0], 0,0,0);
      accX[mt][1] = __builtin_amdgcn_mfma_f32_16x16x32_bf16(wfx, hef[1][kt], accX[mt][1], 0,0,0);
    }
  }

  // ---- trans + x-update ----
  {
    float tp0 = 0.f, tp1 = 0.f;
    #pragma unroll
    for (int mt=0;mt<4;++mt){
      const f32x4 xv4 = *(const f32x4*)&s_xw2v[mt*16 + g*4];
      #pragma unroll
      for (int r=0;r<4;++r){
        tp0 += silu_(accX[mt][0][r])*xv4[r];
        tp1 += silu_(accX[mt][1][r])*xv4[r];
      }
    }
    tp0 += __shfl_xor(tp0,16,64); tp0 += __shfl_xor(tp0,32,64);
    tp1 += __shfl_xor(tp1,16,64); tp1 += __shfl_xor(tp1,32,64);
    const float dx0 = swz_<SWZ_LO>(dx), dx1 = swz_<SWZ_HI>(dx);
    const float dy0 = swz_<SWZ_LO>(dy), dy1 = swz_<SWZ_HI>(dy);
    const float dz0 = swz_<SWZ_LO>(dz), dz1 = swz_<SWZ_HI>(dz);
    const float xa0 = rowsum16(dx0*tp0 + dx1*tp1);
    const float xa1 = rowsum16(dy0*tp0 + dy1*tp1);
    const float xa2 = rowsum16(dz0*tp0 + dz1*tp1);
    if (l == 0){ s_rx[wave*3+0]=xa0; s_rx[wave*3+1]=xa1; s_rx[wave*3+2]=xa2; }
  }

  // ---- c1 -> scratch (sequential), read c1f, cw2-GEMM (regs) ----
  s16x8 c1f[2][2];
  #pragma unroll
  for (int jt=0;jt<2;++jt){
    #pragma unroll
    for (int mt=0;mt<4;++mt){
      const int nb4 = mt*16 + g*4;
      const float c0 = silu_(accC[mt][jt][0]);
      const float c1v= silu_(accC[mt][jt][1]);
      const float c2 = silu_(accC[mt][jt][2]);
      const float c3 = silu_(accC[mt][jt][3]);
      *(uint2*)(myR + ((nb4*2) ^ swzb)) = make_uint2(cvtpk(c0,c1v), cvtpk(c2,c3));
    }
    #pragma unroll
    for (int kt=0;kt<2;++kt){
      c1f[jt][kt] = *(const s16x8*)(myR + (((kt*32 + g*8)*2) ^ swzb));
    }
  }
  f32x4 accW[2][2];
  #pragma unroll
  for (int mt=0;mt<2;++mt){
    const f32x4 bW = *(const f32x4*)&s_cb2[mt*16 + g*4];
    accW[mt][0]=bW; accW[mt][1]=bW;
  }
  #pragma unroll
  for (int kt=0;kt<2;++kt){
    #pragma unroll
    for (int mt=0;mt<2;++mt){
      const s16x8 wf = w2f[mt*2+kt];
      accW[mt][0] = __builtin_amdgcn_mfma_f32_16x16x32_bf16(wf, c1f[0][kt], accW[mt][0], 0,0,0);
      accW[mt][1] = __builtin_amdgcn_mfma_f32_16x16x32_bf16(wf, c1f[1][kt], accW[mt][1], 0,0,0);
    }
  }

  // ---- comb accumulation (DPP row-reduce) ----
  {
    const float u0x = swz_<SWZ_LO>(ux), u1x = swz_<SWZ_HI>(ux);
    const float u0y = swz_<SWZ_LO>(uy), u1y = swz_<SWZ_HI>(uy);
    const float u0z = swz_<SWZ_LO>(uz), u1z = swz_<SWZ_HI>(uz);
    #pragma unroll
    for (int mt=0;mt<2;++mt){
      #pragma unroll
      for (int r=0;r<4;++r){
        const int c = mt*16 + g*4 + r;
        const float cf0 = accW[mt][0][r];
        const float cf1 = accW[mt][1][r];
        const float px = rowsum16(u0x*cf0 + u1x*cf1);
        const float py = rowsum16(u0y*cf0 + u1y*cf1);
        const float pz = rowsum16(u0z*cf0 + u1z*cf1);
        if (r15 == 0){
          s_rc[wave*96 + c*3+0]=px; s_rc[wave*96 + c*3+1]=py; s_rc[wave*96 + c*3+2]=pz;
        }
      }
    }
  }

  __syncthreads();

  // ---- cross-wave reduce -> partials to global ws ----
  float* P = part + (size_t)bi*PSTRIDE;
  if (tid < 64){
    float s = 0.f;
    #pragma unroll
    for (int w=0;w<8;++w) s += s_rh[w*FF + tid];
    P[tid] = s;
  } else if (tid < 160){
    const int t = tid - 64;
    float s = 0.f;
    #pragma unroll
    for (int w=0;w<8;++w) s += s_rc[w*96 + t];
    P[64 + t] = s;
  } else if (tid < 163){
    const int t = tid - 160;
    float s = 0.f;
    #pragma unroll
    for (int w=0;w<8;++w) s += s_rx[w*3 + t];
    P[160 + t] = s;
  }
}

// Kernel C: node-level MLPs. One wave per (b,i).
__global__ __launch_bounds__(64) void sake_node(
    const float* __restrict__ h, const float* __restrict__ x,
    const float* __restrict__ pw1, const float* __restrict__ pb1,
    const float* __restrict__ pw2, const float* __restrict__ pb2,
    const float* __restrict__ nw1, const float* __restrict__ nb1,
    const float* __restrict__ nw2, const float* __restrict__ nb2,
    const float* __restrict__ part, float* __restrict__ out_h, float* __restrict__ out_x)
{
  const int bi = blockIdx.x;
  const int l = threadIdx.x;
  __shared__ float s_cn[NC];
  __shared__ float s_t1[FF];
  __shared__ float s_ni[3*FF];
  const float* P = part + (size_t)bi*PSTRIDE;

  const float hval = h[(size_t)bi*FF + l];
  s_ni[l] = hval;
  s_ni[FF + l] = P[l];                 // hagg
  if (l < NC){
    const float c0 = P[64 + l*3+0];
    const float c1 = P[64 + l*3+1];
    const float c2 = P[64 + l*3+2];
    s_cn[l] = c0*c0 + c1*c1 + c2*c2;
  }
  __syncthreads();
  {
    float a0=0.f,a1=0.f,a2=0.f,a3=0.f;
    #pragma unroll 4
    for (int c=0;c<NC;c+=4){
      a0 += s_cn[c+0]*pw1[(c+0)*FF + l];
      a1 += s_cn[c+1]*pw1[(c+1)*FF + l];
      a2 += s_cn[c+2]*pw1[(c+2)*FF + l];
      a3 += s_cn[c+3]*pw1[(c+3)*FF + l];
    }
    s_t1[l] = silu_(pb1[l] + ((a0+a1)+(a2+a3)));
  }
  __syncthreads();
  {
    float a0=0.f,a1=0.f,a2=0.f,a3=0.f;
    #pragma unroll 4
    for (int k=0;k<FF;k+=4){
      a0 += s_t1[k+0]*pw2[(k+0)*FF + l];
      a1 += s_t1[k+1]*pw2[(k+1)*FF + l];
      a2 += s_t1[k+2]*pw2[(k+2)*FF + l];
      a3 += s_t1[k+3]*pw2[(k+3)*FF + l];
    }
    s_ni[2*FF + l] = pb2[l] + ((a0+a1)+(a2+a3));
  }
  __syncthreads();
  float n1;
  {
    float a0=0.f,a1=0.f,a2=0.f,a3=0.f;
    #pragma unroll 4
    for (int k=0;k<3*FF;k+=4){
      a0 += s_ni[k+0]*nw1[(k+0)*FF + l];
      a1 += s_ni[k+1]*nw1[(k+1)*FF + l];
      a2 += s_ni[k+2]*nw1[(k+2)*FF + l];
      a3 += s_ni[k+3]*nw1[(k+3)*FF + l];
    }
    n1 = silu_(nb1[l] + ((a0+a1)+(a2+a3)));
  }
  __syncthreads();
  s_t1[l] = n1;
  __syncthreads();
  {
    float a0=0.f,a1=0.f,a2=0.f,a3=0.f;
    #pragma unroll 4
    for (int k=0;k<FF;k+=4){
      a0 += s_t1[k+0]*nw2[(k+0)*FF + l];
      a1 += s_t1[k+1]*nw2[(k+1)*FF + l];
      a2 += s_t1[k+2]*nw2[(k+2)*FF + l];
      a3 += s_t1[k+3]*nw2[(k+3)*FF + l];
    }
    out_h[(size_t)bi*FF + l] = hval + nb2[l] + ((a0+a1)+(a2+a3));
    if (l < 3){
      out_x[(size_t)bi*3 + l] = x[(size_t)bi*3 + l] + P[160+l]*(1.0f/256.0f);
    }
  }
}

extern "C" void kernel_launch(void* const* d_in, const int* in_sizes, int n_in,
                              void* d_out, int out_size, void* d_ws, size_t ws_size,
                              hipStream_t stream) {
  const float* h   = (const float*)d_in[0];
  const float* x   = (const float*)d_in[1];
  const float* ew1 = (const float*)d_in[2];
  const float* eb1 = (const float*)d_in[3];
  const float* ew2 = (const float*)d_in[4];
  const float* eb2 = (const float*)d_in[5];
  const float* aw  = (const float*)d_in[6];
  const float* ab  = (const float*)d_in[7];
  const float* cw1 = (const float*)d_in[8];
  const float* cb1 = (const float*)d_in[9];
  const float* cw2 = (const float*)d_in[10];
  const float* cb2 = (const float*)d_in[11];
  const float* pw1 = (const float*)d_in[12];
  const float* pb1 = (const float*)d_in[13];
  const float* pw2 = (const float*)d_in[14];
  const float* pb2 = (const float*)d_in[15];
  const float* nw1 = (const float*)d_in[16];
  const float* nb1 = (const float*)d_in[17];
  const float* nw2 = (const float*)d_in[18];
  const float* nb2 = (const float*)d_in[19];
  const float* xw1 = (const float*)d_in[20];
  const float* xb1 = (const float*)d_in[21];
  const float* xw2 = (const float*)d_in[22];

  float* hip_ = (float*)d_ws;
  float* hjp_ = hip_ + (size_t)NB*NN*FF;
  float* part = hjp_ + (size_t)NB*NN*FF;
  short* wpack = (short*)(part + (size_t)NB*NN*PSTRIDE);
  float* out_h = (float*)d_out;
  float* out_x = out_h + (size_t)NB*NN*FF;

  sake_proj<<<NB*NN, 64, 0, stream>>>(h, ew1, eb1, ew2, cw1, xw1, cw2, hip_, hjp_, wpack);
  sake_main<<<NB*NN, 512, 0, stream>>>(x, ew1, eb2, aw, ab, cb1, cb2, xb1, xw2,
                                       hip_, hjp_, wpack, part);
  sake_node<<<NB*NN, 64, 0, stream>>>(h, x, pw1, pb1, pw2, pb2, nw1, nb1, nw2, nb2,
                                      part, out_h, out_x);
}

// Round 11
// 114.354 us; speedup vs baseline: 1.0565x; 1.0153x over previous
//
#include <hip/hip_runtime.h>
#include <hip/hip_bf16.h>

#define NB 16
#define NN 256
#define FF 64
#define NC 32
#define EPSF 1e-10f
#define PSTRIDE 164   // per-bi partials: 64 hagg + 96 rc + 3 rx (+1 pad)

typedef __attribute__((ext_vector_type(8))) short s16x8;
typedef __attribute__((ext_vector_type(4))) float f32x4;
typedef __attribute__((ext_vector_type(4))) unsigned u32x4;

__device__ __forceinline__ float rcp_(float v){ return __builtin_amdgcn_rcpf(v); }
__device__ __forceinline__ float sigmoid_(float v){ return rcp_(1.0f+__expf(-v)); }
__device__ __forceinline__ float silu_(float v){ return v*rcp_(1.0f+__expf(-v)); }
// packed bf16 convert (RNE), lo16=bf16(a), hi16=bf16(b)
__device__ __forceinline__ unsigned cvtpk(float a, float b){
  unsigned r;
  asm("v_cvt_pk_bf16_f32 %0, %1, %2" : "=v"(r) : "v"(a), "v"(b));
  return r;
}
// DPP-based add of a lane-permuted copy (no DS pipe, no addr setup)
template<int CTRL>
__device__ __forceinline__ float dpp_add(float v){
  int x = __builtin_bit_cast(int, v);
  int y = __builtin_amdgcn_update_dpp(0, x, CTRL, 0xF, 0xF, true);
  return v + __builtin_bit_cast(float, y);
}
// sum over each 16-lane row; all lanes of the row end with the row sum
__device__ __forceinline__ float rowsum16(float v){
  v = dpp_add<0xB1>(v);   // quad_perm xor1
  v = dpp_add<0x4E>(v);   // quad_perm xor2
  v = dpp_add<0x141>(v);  // row_half_mirror
  v = dpp_add<0x140>(v);  // row_mirror
  return v;
}
// ds_swizzle broadcast: src lane = (l & 0xF) | OR  (within each 32-half)
template<int OFF>
__device__ __forceinline__ float swz_(float v){
  int y = __builtin_amdgcn_ds_swizzle(__builtin_bit_cast(int, v), OFF);
  return __builtin_bit_cast(float, y);
}
#define SWZ_LO 0x000F   // src = r15
#define SWZ_HI 0x020F   // src = 16 + r15

// Kernel A: per-node projections + (blocks 0..27) weight pre-packing to d_ws.
__global__ __launch_bounds__(64) void sake_proj(
    const float* __restrict__ h, const float* __restrict__ ew1,
    const float* __restrict__ eb1,
    const float* __restrict__ ew2, const float* __restrict__ cw1,
    const float* __restrict__ xw1, const float* __restrict__ cw2,
    float* __restrict__ hip_, float* __restrict__ hjp_,
    short* __restrict__ wpack)
{
  const int bn = blockIdx.x;
  const int t = threadIdx.x;

  if (bn < 28){
    const int task = bn*64 + t;          // 0..1791
    const int a = task >> 9;             // 0=ew2, 1=cw1, 2=xw1, 3=cw2
    const int s = task & 511;
    const int f = s >> 6, sl = s & 63;
    const int sg = sl >> 4, sr = sl & 15;
    const int mt = f >> 1, kt = f & 1;
    const int ob = mt*16 + sr;
    const int ib = kt*32 + sg*8;
    const float* W = (a==0) ? ew2 : (a==1) ? cw1 : (a==2) ? xw1 : cw2;
    const int ldw = (a==3) ? NC : FF;
    float w[8];
    #pragma unroll
    for (int e=0;e<8;++e) w[e] = W[(ib+e)*ldw + ob];
    u32x4 p;
    p[0]=cvtpk(w[0],w[1]); p[1]=cvtpk(w[2],w[3]); p[2]=cvtpk(w[4],w[5]); p[3]=cvtpk(w[6],w[7]);
    *(u32x4*)&wpack[a*4096 + s*8] = p;
  }

  __shared__ float hs[FF];
  hs[t] = h[bn*FF + t];
  __syncthreads();
  float a1 = eb1[t];
  float a2 = 0.f;
  #pragma unroll 16
  for (int k=0;k<FF;++k){
    const float hv = hs[k];
    a1 += hv * ew1[k*FF + t];
    a2 += hv * ew1[(FF+k)*FF + t];
  }
  hip_[bn*FF + t] = a1;
  hjp_[bn*FF + t] = a2;
}

// Kernel B: one block per (b,i); 8 waves x 32 j; bf16 MFMA, bias-in-C,
// DPP row-reductions, pre-packed weights in LDS, base-folded scratch ptr.
__global__ __launch_bounds__(512, 4) void sake_main(
    const float* __restrict__ x,
    const float* __restrict__ ew1, const float* __restrict__ eb2,
    const float* __restrict__ aw, const float* __restrict__ ab,
    const float* __restrict__ cb1, const float* __restrict__ cb2,
    const float* __restrict__ xb1, const float* __restrict__ xw2,
    const float* __restrict__ hip_, const float* __restrict__ hjp_,
    const short* __restrict__ wpack,
    float* __restrict__ part)
{
  const int bi = blockIdx.x;
  const int b = bi >> 8;
  const int tid = threadIdx.x;
  const int wave = tid >> 6;
  const int l = tid & 63;
  const int g = l >> 4;
  const int r15 = l & 15;

  __shared__ __align__(16) short s_w[14336];   // E@0, C@4096, X@8192, w2@12288 (28KB)
  __shared__ __align__(16) short s_sT[8][1024];// per-wave 2KB act^T scratch, XOR-swizzled
  __shared__ __align__(16) float s_hip[FF], s_e1r[FF], s_eb2[FF], s_cb1[FF], s_xb1[FF], s_xw2v[FF], s_awv[FF];
  __shared__ __align__(16) float s_cb2[NC];
  __shared__ float s_rh[8*FF];
  __shared__ float s_rc[8*NC*3];
  __shared__ float s_rx[8*3];

  // ---- prologue: linear copy of pre-packed weights (28KB) ----
  {
    const u32x4* wp = (const u32x4*)wpack;
    u32x4* wd = (u32x4*)s_w;
    wd[tid]       = wp[tid];
    wd[tid+512]   = wp[tid+512];
    wd[tid+1024]  = wp[tid+1024];
    if (tid < 256) wd[tid+1536] = wp[tid+1536];
  }
  if (tid < FF){
    s_hip[tid]  = hip_[(size_t)bi*FF + tid];
    s_e1r[tid]  = ew1[128*FF + tid];
    s_eb2[tid]  = eb2[tid];
    s_cb1[tid]  = cb1[tid];
    s_xb1[tid]  = xb1[tid];
    s_xw2v[tid] = xw2[tid];
    s_awv[tid]  = aw[tid];
  } else if (tid < FF + NC){
    s_cb2[tid-FF] = cb2[tid-FF];
  }
  __syncthreads();

  const float abv = ab[0];
  const float xi0 = x[(size_t)bi*3+0], xi1 = x[(size_t)bi*3+1], xi2 = x[(size_t)bi*3+2];

  // ---- geometry in registers: lane l holds jl = l&31 ----
  float dx, dy, dz, nr, ux, uy, uz;
  {
    const int jl = l & 31;
    const int j  = wave*32 + jl;
    const float xj0 = x[((size_t)(b*NN+j))*3+0];
    const float xj1 = x[((size_t)(b*NN+j))*3+1];
    const float xj2 = x[((size_t)(b*NN+j))*3+2];
    dx = xi0-xj0; dy = xi1-xj1; dz = xi2-xj2;
    nr = __builtin_amdgcn_sqrtf(dx*dx+dy*dy+dz*dz+EPSF);
    const float inr = rcp_(nr + EPSF);
    ux = dx*inr; uy = dy*inr; uz = dz*inr;
  }

  // ---- hoisted hp/e1 slices (reused across jt) ----
  float4 hp0v[2], hp1v[2], e10v[2], e11v[2];
  #pragma unroll
  for (int kt=0;kt<2;++kt){
    const int fb = kt*32 + g*8;
    hp0v[kt] = *(const float4*)&s_hip[fb];
    hp1v[kt] = *(const float4*)&s_hip[fb+4];
    e10v[kt] = *(const float4*)&s_e1r[fb];
    e11v[kt] = *(const float4*)&s_e1r[fb+4];
  }

  // ---- a1 B-frags: slot(l,e) = a1[j=jt*16+r15][feat=kt*32+g*8+e] ----
  s16x8 a1f[2][2];
  #pragma unroll
  for (int jt=0;jt<2;++jt){
    const float nrj = jt ? swz_<SWZ_HI>(nr) : swz_<SWZ_LO>(nr);
    const float* hrow = &hjp_[((size_t)(b*NN + wave*32 + jt*16 + r15))*FF];
    #pragma unroll
    for (int kt=0;kt<2;++kt){
      const int fb = kt*32 + g*8;
      const float4 hj0 = *(const float4*)&hrow[fb];
      const float4 hj1 = *(const float4*)&hrow[fb+4];
      const float v0 = silu_(hp0v[kt].x + hj0.x + nrj*e10v[kt].x);
      const float v1 = silu_(hp0v[kt].y + hj0.y + nrj*e10v[kt].y);
      const float v2 = silu_(hp0v[kt].z + hj0.z + nrj*e10v[kt].z);
      const float v3 = silu_(hp0v[kt].w + hj0.w + nrj*e10v[kt].w);
      const float v4 = silu_(hp1v[kt].x + hj1.x + nrj*e11v[kt].x);
      const float v5 = silu_(hp1v[kt].y + hj1.y + nrj*e11v[kt].y);
      const float v6 = silu_(hp1v[kt].z + hj1.z + nrj*e11v[kt].z);
      const float v7 = silu_(hp1v[kt].w + hj1.w + nrj*e11v[kt].w);
      u32x4 p; p[0]=cvtpk(v0,v1); p[1]=cvtpk(v2,v3); p[2]=cvtpk(v4,v5); p[3]=cvtpk(v6,v7);
      a1f[jt][kt] = __builtin_bit_cast(s16x8, p);
    }
  }

  // ---- E-GEMM with bias-in-C ----
  f32x4 accE[4][2];
  #pragma unroll
  for (int mt=0;mt<4;++mt){
    const f32x4 bE = *(const f32x4*)&s_eb2[mt*16 + g*4];
    accE[mt][0] = bE; accE[mt][1] = bE;
  }
  #pragma unroll
  for (int kt=0;kt<2;++kt){
    #pragma unroll
    for (int mt=0;mt<4;++mt){
      const s16x8 wf = *(const s16x8*)&s_w[((mt*2+kt)*64 + l)*8];
      accE[mt][0] = __builtin_amdgcn_mfma_f32_16x16x32_bf16(wf, a1f[0][kt], accE[mt][0], 0,0,0);
      accE[mt][1] = __builtin_amdgcn_mfma_f32_16x16x32_bf16(wf, a1f[1][kt], accE[mt][1], 0,0,0);
    }
  }

  // ---- silu, att gate ----
  float hg[4][2][4];
  float att0p = 0.f, att1p = 0.f;
  #pragma unroll
  for (int mt=0;mt<4;++mt){
    const f32x4 awv4 = *(const f32x4*)&s_awv[mt*16 + g*4];
    #pragma unroll
    for (int r=0;r<4;++r){
      const float v0 = silu_(accE[mt][0][r]);
      const float v1 = silu_(accE[mt][1][r]);
      hg[mt][0][r] = v0; hg[mt][1][r] = v1;
      att0p += v0*awv4[r]; att1p += v1*awv4[r];
    }
  }
  att0p += __shfl_xor(att0p,16,64); att0p += __shfl_xor(att0p,32,64);
  att1p += __shfl_xor(att1p,16,64); att1p += __shfl_xor(att1p,32,64);
  const float att0 = sigmoid_(att0p + abv);
  const float att1 = sigmoid_(att1p + abv);

  #pragma unroll
  for (int mt=0;mt<4;++mt){
    #pragma unroll
    for (int r=0;r<4;++r){
      const float h0 = hg[mt][0][r]*att0;
      const float h1 = hg[mt][1][r]*att1;
      hg[mt][0][r] = h0; hg[mt][1][r] = h1;
      const float hpv = rowsum16(h0 + h1);
      if (r15 == 0) s_rh[wave*FF + mt*16 + g*4 + r] = hpv;
    }
  }

  // ---- he^T -> 2KB scratch (base-folded), sequential 16-j tiles ----
  char* myR = (char*)&s_sT[wave][0] + r15*128;
  const int swzb = (r15 & 7) << 4;
  s16x8 hef[2][2];
  #pragma unroll
  for (int jt=0;jt<2;++jt){
    #pragma unroll
    for (int mt=0;mt<4;++mt){
      const unsigned p0 = cvtpk(hg[mt][jt][0], hg[mt][jt][1]);
      const unsigned p1 = cvtpk(hg[mt][jt][2], hg[mt][jt][3]);
      *(uint2*)(myR + (((mt*16 + g*4)*2) ^ swzb)) = make_uint2(p0, p1);
    }
    #pragma unroll
    for (int kt=0;kt<2;++kt){
      hef[jt][kt] = *(const s16x8*)(myR + (((kt*32 + g*8)*2) ^ swzb));
    }
  }

  // ---- cw1-GEMM and xw1-GEMM with bias-in-C ----
  f32x4 accC[4][2], accX[4][2];
  #pragma unroll
  for (int mt=0;mt<4;++mt){
    const f32x4 bC = *(const f32x4*)&s_cb1[mt*16 + g*4];
    const f32x4 bX = *(const f32x4*)&s_xb1[mt*16 + g*4];
    accC[mt][0]=bC; accC[mt][1]=bC;
    accX[mt][0]=bX; accX[mt][1]=bX;
  }
  #pragma unroll
  for (int kt=0;kt<2;++kt){
    #pragma unroll
    for (int mt=0;mt<4;++mt){
      const s16x8 wfc = *(const s16x8*)&s_w[4096 + ((mt*2+kt)*64 + l)*8];
      accC[mt][0] = __builtin_amdgcn_mfma_f32_16x16x32_bf16(wfc, hef[0][kt], accC[mt][0], 0,0,0);
      accC[mt][1] = __builtin_amdgcn_mfma_f32_16x16x32_bf16(wfc, hef[1][kt], accC[mt][1], 0,0,0);
      const s16x8 wfx = *(const s16x8*)&s_w[8192 + ((mt*2+kt)*64 + l)*8];
      accX[mt][0] = __builtin_amdgcn_mfma_f32_16x16x32_bf16(wfx, hef[0][kt], accX[mt][0], 0,0,0);
      accX[mt][1] = __builtin_amdgcn_mfma_f32_16x16x32_bf16(wfx, hef[1][kt], accX[mt][1], 0,0,0);
    }
  }

  // ---- trans + x-update ----
  {
    float tp0 = 0.f, tp1 = 0.f;
    #pragma unroll
    for (int mt=0;mt<4;++mt){
      const f32x4 xv4 = *(const f32x4*)&s_xw2v[mt*16 + g*4];
      #pragma unroll
      for (int r=0;r<4;++r){
        tp0 += silu_(accX[mt][0][r])*xv4[r];
        tp1 += silu_(accX[mt][1][r])*xv4[r];
      }
    }
    tp0 += __shfl_xor(tp0,16,64); tp0 += __shfl_xor(tp0,32,64);
    tp1 += __shfl_xor(tp1,16,64); tp1 += __shfl_xor(tp1,32,64);
    const float dx0 = swz_<SWZ_LO>(dx), dx1 = swz_<SWZ_HI>(dx);
    const float dy0 = swz_<SWZ_LO>(dy), dy1 = swz_<SWZ_HI>(dy);
    const float dz0 = swz_<SWZ_LO>(dz), dz1 = swz_<SWZ_HI>(dz);
    const float xa0 = rowsum16(dx0*tp0 + dx1*tp1);
    const float xa1 = rowsum16(dy0*tp0 + dy1*tp1);
    const float xa2 = rowsum16(dz0*tp0 + dz1*tp1);
    if (l == 0){ s_rx[wave*3+0]=xa0; s_rx[wave*3+1]=xa1; s_rx[wave*3+2]=xa2; }
  }

  // ---- c1 -> scratch (sequential), read c1f, cw2-GEMM ----
  s16x8 c1f[2][2];
  #pragma unroll
  for (int jt=0;jt<2;++jt){
    #pragma unroll
    for (int mt=0;mt<4;++mt){
      const int nb4 = mt*16 + g*4;
      const float c0 = silu_(accC[mt][jt][0]);
      const float c1v= silu_(accC[mt][jt][1]);
      const float c2 = silu_(accC[mt][jt][2]);
      const float c3 = silu_(accC[mt][jt][3]);
      *(uint2*)(myR + ((nb4*2) ^ swzb)) = make_uint2(cvtpk(c0,c1v), cvtpk(c2,c3));
    }
    #pragma unroll
    for (int kt=0;kt<2;++kt){
      c1f[jt][kt] = *(const s16x8*)(myR + (((kt*32 + g*8)*2) ^ swzb));
    }
  }
  f32x4 accW[2][2];
  #pragma unroll
  for (int mt=0;mt<2;++mt){
    const f32x4 bW = *(const f32x4*)&s_cb2[mt*16 + g*4];
    accW[mt][0]=bW; accW[mt][1]=bW;
  }
  #pragma unroll
  for (int kt=0;kt<2;++kt){
    #pragma unroll
    for (int mt=0;mt<2;++mt){
      const s16x8 wf = *(const s16x8*)&s_w[12288 + ((mt*2+kt)*64 + l)*8];
      accW[mt][0] = __builtin_amdgcn_mfma_f32_16x16x32_bf16(wf, c1f[0][kt], accW[mt][0], 0,0,0);
      accW[mt][1] = __builtin_amdgcn_mfma_f32_16x16x32_bf16(wf, c1f[1][kt], accW[mt][1], 0,0,0);
    }
  }

  // ---- comb accumulation (DPP row-reduce) ----
  {
    const float u0x = swz_<SWZ_LO>(ux), u1x = swz_<SWZ_HI>(ux);
    const float u0y = swz_<SWZ_LO>(uy), u1y = swz_<SWZ_HI>(uy);
    const float u0z = swz_<SWZ_LO>(uz), u1z = swz_<SWZ_HI>(uz);
    #pragma unroll
    for (int mt=0;mt<2;++mt){
      #pragma unroll
      for (int r=0;r<4;++r){
        const int c = mt*16 + g*4 + r;
        const float cf0 = accW[mt][0][r];
        const float cf1 = accW[mt][1][r];
        const float px = rowsum16(u0x*cf0 + u1x*cf1);
        const float py = rowsum16(u0y*cf0 + u1y*cf1);
        const float pz = rowsum16(u0z*cf0 + u1z*cf1);
        if (r15 == 0){
          s_rc[wave*96 + c*3+0]=px; s_rc[wave*96 + c*3+1]=py; s_rc[wave*96 + c*3+2]=pz;
        }
      }
    }
  }

  __syncthreads();

  // ---- cross-wave reduce -> partials to global ws ----
  float* P = part + (size_t)bi*PSTRIDE;
  if (tid < 64){
    float s = 0.f;
    #pragma unroll
    for (int w=0;w<8;++w) s += s_rh[w*FF + tid];
    P[tid] = s;
  } else if (tid < 160){
    const int t = tid - 64;
    float s = 0.f;
    #pragma unroll
    for (int w=0;w<8;++w) s += s_rc[w*96 + t];
    P[64 + t] = s;
  } else if (tid < 163){
    const int t = tid - 160;
    float s = 0.f;
    #pragma unroll
    for (int w=0;w<8;++w) s += s_rx[w*3 + t];
    P[160 + t] = s;
  }
}

// Kernel C: node-level MLPs. One wave per (b,i).
__global__ __launch_bounds__(64) void sake_node(
    const float* __restrict__ h, const float* __restrict__ x,
    const float* __restrict__ pw1, const float* __restrict__ pb1,
    const float* __restrict__ pw2, const float* __restrict__ pb2,
    const float* __restrict__ nw1, const float* __restrict__ nb1,
    const float* __restrict__ nw2, const float* __restrict__ nb2,
    const float* __restrict__ part, float* __restrict__ out_h, float* __restrict__ out_x)
{
  const int bi = blockIdx.x;
  const int l = threadIdx.x;
  __shared__ float s_cn[NC];
  __shared__ float s_t1[FF];
  __shared__ float s_ni[3*FF];
  const float* P = part + (size_t)bi*PSTRIDE;

  const float hval = h[(size_t)bi*FF + l];
  s_ni[l] = hval;
  s_ni[FF + l] = P[l];                 // hagg
  if (l < NC){
    const float c0 = P[64 + l*3+0];
    const float c1 = P[64 + l*3+1];
    const float c2 = P[64 + l*3+2];
    s_cn[l] = c0*c0 + c1*c1 + c2*c2;
  }
  __syncthreads();
  {
    float a0=0.f,a1=0.f,a2=0.f,a3=0.f;
    #pragma unroll 4
    for (int c=0;c<NC;c+=4){
      a0 += s_cn[c+0]*pw1[(c+0)*FF + l];
      a1 += s_cn[c+1]*pw1[(c+1)*FF + l];
      a2 += s_cn[c+2]*pw1[(c+2)*FF + l];
      a3 += s_cn[c+3]*pw1[(c+3)*FF + l];
    }
    s_t1[l] = silu_(pb1[l] + ((a0+a1)+(a2+a3)));
  }
  __syncthreads();
  {
    float a0=0.f,a1=0.f,a2=0.f,a3=0.f;
    #pragma unroll 4
    for (int k=0;k<FF;k+=4){
      a0 += s_t1[k+0]*pw2[(k+0)*FF + l];
      a1 += s_t1[k+1]*pw2[(k+1)*FF + l];
      a2 += s_t1[k+2]*pw2[(k+2)*FF + l];
      a3 += s_t1[k+3]*pw2[(k+3)*FF + l];
    }
    s_ni[2*FF + l] = pb2[l] + ((a0+a1)+(a2+a3));
  }
  __syncthreads();
  float n1;
  {
    float a0=0.f,a1=0.f,a2=0.f,a3=0.f;
    #pragma unroll 4
    for (int k=0;k<3*FF;k+=4){
      a0 += s_ni[k+0]*nw1[(k+0)*FF + l];
      a1 += s_ni[k+1]*nw1[(k+1)*FF + l];
      a2 += s_ni[k+2]*nw1[(k+2)*FF + l];
      a3 += s_ni[k+3]*nw1[(k+3)*FF + l];
    }
    n1 = silu_(nb1[l] + ((a0+a1)+(a2+a3)));
  }
  __syncthreads();
  s_t1[l] = n1;
  __syncthreads();
  {
    float a0=0.f,a1=0.f,a2=0.f,a3=0.f;
    #pragma unroll 4
    for (int k=0;k<FF;k+=4){
      a0 += s_t1[k+0]*nw2[(k+0)*FF + l];
      a1 += s_t1[k+1]*nw2[(k+1)*FF + l];
      a2 += s_t1[k+2]*nw2[(k+2)*FF + l];
      a3 += s_t1[k+3]*nw2[(k+3)*FF + l];
    }
    out_h[(size_t)bi*FF + l] = hval + nb2[l] + ((a0+a1)+(a2+a3));
    if (l < 3){
      out_x[(size_t)bi*3 + l] = x[(size_t)bi*3 + l] + P[160+l]*(1.0f/256.0f);
    }
  }
}

extern "C" void kernel_launch(void* const* d_in, const int* in_sizes, int n_in,
                              void* d_out, int out_size, void* d_ws, size_t ws_size,
                              hipStream_t stream) {
  const float* h   = (const float*)d_in[0];
  const float* x   = (const float*)d_in[1];
  const float* ew1 = (const float*)d_in[2];
  const float* eb1 = (const float*)d_in[3];
  const float* ew2 = (const float*)d_in[4];
  const float* eb2 = (const float*)d_in[5];
  const float* aw  = (const float*)d_in[6];
  const float* ab  = (const float*)d_in[7];
  const float* cw1 = (const float*)d_in[8];
  const float* cb1 = (const float*)d_in[9];
  const float* cw2 = (const float*)d_in[10];
  const float* cb2 = (const float*)d_in[11];
  const float* pw1 = (const float*)d_in[12];
  const float* pb1 = (const float*)d_in[13];
  const float* pw2 = (const float*)d_in[14];
  const float* pb2 = (const float*)d_in[15];
  const float* nw1 = (const float*)d_in[16];
  const float* nb1 = (const float*)d_in[17];
  const float* nw2 = (const float*)d_in[18];
  const float* nb2 = (const float*)d_in[19];
  const float* xw1 = (const float*)d_in[20];
  const float* xb1 = (const float*)d_in[21];
  const float* xw2 = (const float*)d_in[22];

  float* hip_ = (float*)d_ws;
  float* hjp_ = hip_ + (size_t)NB*NN*FF;
  float* part = hjp_ + (size_t)NB*NN*FF;
  short* wpack = (short*)(part + (size_t)NB*NN*PSTRIDE);
  float* out_h = (float*)d_out;
  float* out_x = out_h + (size_t)NB*NN*FF;

  sake_proj<<<NB*NN, 64, 0, stream>>>(h, ew1, eb1, ew2, cw1, xw1, cw2, hip_, hjp_, wpack);
  sake_main<<<NB*NN, 512, 0, stream>>>(x, ew1, eb2, aw, ab, cb1, cb2, xb1, xw2,
                                       hip_, hjp_, wpack, part);
  sake_node<<<NB*NN, 64, 0, stream>>>(h, x, pw1, pb1, pw2, pb2, nw1, nb1, nw2, nb2,
                                      part, out_h, out_x);
}